// Round 2
// baseline (2376.135 us; speedup 1.0000x reference)
//
#include <hip/hip_runtime.h>
#include <hip/hip_bf16.h>
#include <math.h>

#define NN 15000
#define NE 60000
#define NB 512
#define DDIM 64
#define NIF 15
#define EIF 5
#define EHID 128
#define NSTEP 6
#define EPB 128   // edges per k_msg block (2 waves x 64)
#define KCH 258   // K-chunks of 32: 256 normal (K=8192) + 2 bias rows (K=64)

typedef _Float16 half8 __attribute__((ext_vector_type(8)));
typedef float floatx4 __attribute__((ext_vector_type(4)));

__device__ __forceinline__ float sigmoidf_(float x) { return 1.f / (1.f + expf(-x)); }

// ---- sentinel: written iff workspace guard trips (diagnostic channel) ----
__global__ void k_sentinel(float* out) { out[0] = 1000.0f; }

// ---- degree (counts) ----
__global__ void k_deg(const int* __restrict__ tgt, float* __restrict__ deg) {
  int e = blockIdx.x * 256 + threadIdx.x;
  if (e < NE) atomicAdd(&deg[tgt[e]], 1.0f);
}

// ---- per-graph node ranges (batch sorted) ----
__global__ void k_bounds(const int* __restrict__ batch, int* __restrict__ gstart,
                         int* __restrict__ gend) {
  int n = blockIdx.x * 256 + threadIdx.x;
  if (n < NN) {
    int b = batch[n];
    atomicMin(&gstart[b], n);
    atomicMax(&gend[b], n + 1);
  }
}

// ---- lin0 + relu ----
__global__ void k_lin0(const float* __restrict__ x, const float* __restrict__ w,
                       const float* __restrict__ b, float* __restrict__ out) {
  int idx = blockIdx.x * 256 + threadIdx.x;
  if (idx >= NN * DDIM) return;
  int n = idx >> 6, d = idx & 63;
  float s = b[d];
#pragma unroll
  for (int i = 0; i < NIF; ++i) s += x[n * NIF + i] * w[d * NIF + i];
  out[idx] = fmaxf(s, 0.f);
}

// ---- repack en_w2 (+b2 as 64 extra K-rows) into B-fragment order, f16 ----
// W2pp[g][o][j], g=k>>3 in [0,1032): lane loads 16B contiguous per MFMA B-frag.
// g<1024: k=g*8+j, i=k>>7, h=k&127, src=en_w2[(i*64+o)*128+h]
// g>=1024: i=(g-1024)*8+j, src=b2[i*64+o]
__global__ void k_pack(const float* __restrict__ w2, const float* __restrict__ b2,
                       _Float16* __restrict__ w2pp) {
  int idx = blockIdx.x * 256 + threadIdx.x;  // 1032*512 = 528384 total
  if (idx >= 1032 * 512) return;
  int g = idx >> 9;
  int r = idx & 511;
  int o = r >> 3, j = r & 7;
  float v;
  if (g < 1024) {
    int i = g >> 4;
    int h = ((g & 15) << 3) + j;
    v = w2[(size_t)(i * 64 + o) * 128 + h];
  } else {
    int i = ((g - 1024) << 3) + j;
    v = b2[i * 64 + o];
  }
  w2pp[idx] = (_Float16)v;
}

// ---- fused message pass: agg[tgt[e]][o] += sum_i out[src[e]][i] * ew[e][i][o]
// ew recomputed on the fly: A[e][i*128+h] = os[i]*hid[h] (rank-1, built in-reg),
// bias b2 folded in as K-rows 8192..8255 (A = os[i], B = b2).
// Block: 128 threads = 2 waves; each wave: 64 private edges, M=4x16, N=64, K=8256.
__global__ __launch_bounds__(128) void k_msg(
    const float* __restrict__ outv, const float* __restrict__ ea,
    const float* __restrict__ w1, const float* __restrict__ b1,
    const _Float16* __restrict__ w2pp, const int* __restrict__ src,
    const int* __restrict__ tgt, float* __restrict__ agg) {
  // strides: hid row 136 f16 = 272B (16B-aligned, banks stride 4 -> 2-way, free)
  //          os  row  72 f16 = 144B (16B-aligned, banks stride 4 -> 2-way, free)
  __shared__ __align__(16) _Float16 hidL[EPB][136];
  __shared__ __align__(16) _Float16 osL[EPB][72];
  __shared__ float w1L[768];  // 128x5 w1 then 128 b1
  int tid = threadIdx.x;
  int e0 = blockIdx.x * EPB;

  for (int idx = tid; idx < 768; idx += EPB)
    w1L[idx] = (idx < 640) ? w1[idx] : b1[idx - 640];

  // gather out[src[e]] -> osL (f16), one edge per thread
  int e = e0 + tid;
  bool valid = e < NE;
  int s = valid ? src[e] : 0;
  const float4* op = (const float4*)(outv + (size_t)s * 64);
#pragma unroll
  for (int qq = 0; qq < 16; ++qq) {
    float4 v = op[qq];
    if (!valid) v = make_float4(0.f, 0.f, 0.f, 0.f);
    osL[tid][qq * 4 + 0] = (_Float16)v.x;
    osL[tid][qq * 4 + 1] = (_Float16)v.y;
    osL[tid][qq * 4 + 2] = (_Float16)v.z;
    osL[tid][qq * 4 + 3] = (_Float16)v.w;
  }
  float eav[EIF];
#pragma unroll
  for (int i = 0; i < EIF; ++i) eav[i] = valid ? ea[e * EIF + i] : 0.f;
  __syncthreads();  // w1L ready

  // hid[e] = relu(ea @ W1^T + b1), one edge per thread
  for (int h = 0; h < EHID; ++h) {
    float sum = w1L[640 + h];
#pragma unroll
    for (int i = 0; i < EIF; ++i) sum += eav[i] * w1L[h * EIF + i];
    hidL[tid][h] = (_Float16)fmaxf(sum, 0.f);
  }
  __syncthreads();  // hidL/osL ready

  int wv = tid >> 6, lane = tid & 63;
  int l15 = lane & 15, q = lane >> 4;
  int rbase = wv * 64 + l15;  // LDS row base for this lane's A-rows (+ m*16)

  floatx4 acc[4][4];
#pragma unroll
  for (int m = 0; m < 4; ++m)
#pragma unroll
    for (int og = 0; og < 4; ++og) acc[m][og] = (floatx4){0.f, 0.f, 0.f, 0.f};

  for (int c = 0; c < KCH; ++c) {
    half8 af[4];
    if (c < 256) {
      int i = c >> 2;                          // k>>7
      int h0 = ((c & 3) << 5) + (q << 3);      // k&127 base for this quad
#pragma unroll
      for (int m = 0; m < 4; ++m) {
        int row = rbase + m * 16;
        half8 hv = *(const half8*)&hidL[row][h0];
        _Float16 ov = osL[row][i];
        half8 osp = {ov, ov, ov, ov, ov, ov, ov, ov};
        af[m] = hv * osp;                      // v_pk_mul_f16
      }
    } else {                                   // bias rows: A = os directly
      int i0 = ((c - 256) << 5) + (q << 3);
#pragma unroll
      for (int m = 0; m < 4; ++m)
        af[m] = *(const half8*)&osL[rbase + m * 16][i0];
    }
    const _Float16* bp = w2pp + ((size_t)(c * 4 + q) * 64 + l15) * 8;
#pragma unroll
    for (int og = 0; og < 4; ++og) {
      half8 bf = *(const half8*)(bp + og * 128);  // og*16 outputs * 8 j
#pragma unroll
      for (int m = 0; m < 4; ++m)
        acc[m][og] = __builtin_amdgcn_mfma_f32_16x16x32_f16(af[m], bf, acc[m][og], 0, 0, 0);
    }
  }

  // epilogue: C/D layout row=(lane>>4)*4+j (edge), col=lane&15 (o within og*16)
#pragma unroll
  for (int m = 0; m < 4; ++m) {
    int erow = e0 + wv * 64 + m * 16 + q * 4;
#pragma unroll
    for (int j = 0; j < 4; ++j) {
      int ee = erow + j;
      if (ee < NE) {
        int t = tgt[ee];
        float* ap = agg + (size_t)t * 64 + l15;
#pragma unroll
        for (int og = 0; og < 4; ++og) atomicAdd(ap + og * 16, acc[m][og][j]);
      }
    }
  }
}

// ---- GRU step: m = relu(agg/deg + conv_b); h' = GRU(m, h); out = h' ----
__global__ __launch_bounds__(256) void k_gru(
    const float* __restrict__ agg, const float* __restrict__ deg,
    const float* __restrict__ convb, const float* __restrict__ wih,
    const float* __restrict__ whh, const float* __restrict__ bih,
    const float* __restrict__ bhh, float* __restrict__ out) {
  __shared__ float mld[8 * 64], hld[8 * 64], gild[8 * 192], ghld[8 * 192];
  int tid = threadIdx.x;
  int n0 = blockIdx.x * 8;
#pragma unroll
  for (int r = 0; r < 2; ++r) {
    int idx = r * 256 + tid;
    int nl = idx >> 6, d = idx & 63;
    int n = n0 + nl;
    float dg = fmaxf(deg[n], 1.0f);
    mld[idx] = fmaxf(agg[n * 64 + d] / dg + convb[d], 0.f);
    hld[idx] = out[n * 64 + d];
  }
  __syncthreads();
  for (int r = 0; r < 12; ++r) {
    int idx = r * 256 + tid;  // 3072 = 8 nodes * 192 gates * 2 (gi,gh)
    int nl = idx / 384;
    int rem = idx % 384;
    int kind = rem / 192, g = rem % 192;
    const float* W = kind ? whh : wih;
    const float* vec = kind ? &hld[nl * 64] : &mld[nl * 64];
    float s = kind ? bhh[g] : bih[g];
    for (int i = 0; i < 64; ++i) s += vec[i] * W[g * 64 + i];
    (kind ? ghld : gild)[nl * 192 + g] = s;
  }
  __syncthreads();
#pragma unroll
  for (int r = 0; r < 2; ++r) {
    int idx = r * 256 + tid;
    int nl = idx >> 6, d = idx & 63;
    float ir = gild[nl * 192 + d], hr = ghld[nl * 192 + d];
    float iz = gild[nl * 192 + 64 + d], hz = ghld[nl * 192 + 64 + d];
    float in_ = gild[nl * 192 + 128 + d], hn = ghld[nl * 192 + 128 + d];
    float rg = sigmoidf_(ir + hr);
    float zg = sigmoidf_(iz + hz);
    float ng = tanhf(in_ + rg * hn);
    float h = hld[idx];
    out[(n0 + nl) * 64 + d] = (1.f - zg) * ng + zg * h;
  }
}

// ---- Set2Set LSTM gates ----
__global__ __launch_bounds__(256) void k_lstm_g(
    const float* __restrict__ qstar, const float* __restrict__ hl,
    const float* __restrict__ wih, const float* __restrict__ whh,
    const float* __restrict__ bih, const float* __restrict__ bhh,
    float* __restrict__ g) {
  __shared__ float q[128], h[64];
  int b = blockIdx.x, j = threadIdx.x;
  if (j < 128) q[j] = qstar[b * 128 + j];
  if (j < 64) h[j] = hl[b * 64 + j];
  __syncthreads();
  float s = bih[j] + bhh[j];
  for (int k = 0; k < 128; ++k) s += q[k] * wih[j * 128 + k];
  for (int k = 0; k < 64; ++k) s += h[k] * whh[j * 64 + k];
  g[b * 256 + j] = s;
}

__global__ void k_lstm_upd(const float* __restrict__ g, float* __restrict__ cl,
                           float* __restrict__ hl) {
  int idx = blockIdx.x * 256 + threadIdx.x;
  if (idx >= NB * 64) return;
  int b = idx >> 6, d = idx & 63;
  float ig = g[b * 256 + d], fg = g[b * 256 + 64 + d];
  float gg = g[b * 256 + 128 + d], og = g[b * 256 + 192 + d];
  float c = sigmoidf_(fg) * cl[idx] + sigmoidf_(ig) * tanhf(gg);
  cl[idx] = c;
  hl[idx] = sigmoidf_(og) * tanhf(c);
}

// ---- attention softmax + weighted sum; q_star = [hl, rvec] ----
__global__ __launch_bounds__(64) void k_attn(
    const float* __restrict__ out, const float* __restrict__ hl,
    const int* __restrict__ gstart, const int* __restrict__ gend,
    float* __restrict__ qstar) {
  int b = blockIdx.x, d = threadIdx.x;
  float hd = hl[b * 64 + d];
  int s = gstart[b], e = gend[b];
  float mx = -1e30f;
  for (int n = s; n < e; ++n) {
    float v = out[n * 64 + d] * hd;
#pragma unroll
    for (int off = 32; off > 0; off >>= 1) v += __shfl_xor(v, off);
    mx = fmaxf(mx, v);
  }
  float sum = 0.f, acc = 0.f;
  for (int n = s; n < e; ++n) {
    float o_nd = out[n * 64 + d];
    float v = o_nd * hd;
#pragma unroll
    for (int off = 32; off > 0; off >>= 1) v += __shfl_xor(v, off);
    float ex = expf(v - mx);
    sum += ex;
    acc += ex * o_nd;
  }
  qstar[b * 128 + d] = hd;
  qstar[b * 128 + 64 + d] = acc / (sum + 1e-16f);
}

// ---- head ----
__global__ __launch_bounds__(64) void k_final(
    const float* __restrict__ qstar, const float* __restrict__ w1,
    const float* __restrict__ b1, const float* __restrict__ w2,
    const float* __restrict__ b2, float* __restrict__ y) {
  __shared__ float hid[64];
  int b = blockIdx.x, d = threadIdx.x;
  float s = b1[d];
  for (int k = 0; k < 128; ++k) s += qstar[b * 128 + k] * w1[d * 128 + k];
  hid[d] = fmaxf(s, 0.f);
  __syncthreads();
  if (d < 12) {
    float s2 = b2[d];
    for (int k = 0; k < 64; ++k) s2 += hid[k] * w2[d * 64 + k];
    y[b * 12 + d] = s2;
  }
}

extern "C" void kernel_launch(void* const* d_in, const int* in_sizes, int n_in,
                              void* d_out, int out_size, void* d_ws, size_t ws_size,
                              hipStream_t stream) {
  const float* x = (const float*)d_in[0];
  const float* ea = (const float*)d_in[1];
  const int* eidx = (const int*)d_in[2];
  const int* batch = (const int*)d_in[3];
  const float* lin0_w = (const float*)d_in[4];
  const float* lin0_b = (const float*)d_in[5];
  const float* en_w1 = (const float*)d_in[6];
  const float* en_b1 = (const float*)d_in[7];
  const float* en_w2 = (const float*)d_in[8];
  const float* en_b2 = (const float*)d_in[9];
  const float* conv_b = (const float*)d_in[10];
  const float* gru_wih = (const float*)d_in[11];
  const float* gru_whh = (const float*)d_in[12];
  const float* gru_bih = (const float*)d_in[13];
  const float* gru_bhh = (const float*)d_in[14];
  const float* lstm_wih = (const float*)d_in[15];
  const float* lstm_whh = (const float*)d_in[16];
  const float* lstm_bih = (const float*)d_in[17];
  const float* lstm_bhh = (const float*)d_in[18];
  const float* lin1_w = (const float*)d_in[19];
  const float* lin1_b = (const float*)d_in[20];
  const float* lin2_w = (const float*)d_in[21];
  const float* lin2_b = (const float*)d_in[22];
  const int* srcp = eidx;
  const int* tgtp = eidx + NE;

  char* ws = (char*)d_ws;
  size_t off = 0;
  auto alloc = [&](size_t bytes) {
    char* p = ws + off;
    off += (bytes + 255) & ~(size_t)255;
    return p;
  };
  _Float16* w2pp = (_Float16*)alloc((size_t)1032 * 512 * 2);  // 1.06 MB
  float* out = (float*)alloc((size_t)NN * 64 * 4);            // 3.84 MB
  float* agg = (float*)alloc((size_t)NN * 64 * 4);            // 3.84 MB
  float* deg = (float*)alloc((size_t)NN * 4);
  int* gstart = (int*)alloc((size_t)NB * 4);
  int* gend = (int*)alloc((size_t)NB * 4);
  float* hl = (float*)alloc((size_t)NB * 64 * 4);
  float* cl = (float*)alloc((size_t)NB * 64 * 4);
  float* qstar = (float*)alloc((size_t)NB * 128 * 4);
  float* gbuf = (float*)alloc((size_t)NB * 256 * 4);
  if (off > ws_size) {  // ~9.8 MB total; if this trips, absmax ~= 1000 tells us
    k_sentinel<<<1, 1, 0, stream>>>((float*)d_out);
    return;
  }

  hipMemsetAsync(deg, 0, (size_t)NN * 4, stream);
  hipMemsetAsync(gstart, 0x7f, (size_t)NB * 4, stream);
  hipMemsetAsync(gend, 0, (size_t)NB * 4, stream);
  hipMemsetAsync(hl, 0, (size_t)NB * 64 * 4, stream);
  hipMemsetAsync(cl, 0, (size_t)NB * 64 * 4, stream);
  hipMemsetAsync(qstar, 0, (size_t)NB * 128 * 4, stream);

  k_deg<<<(NE + 255) / 256, 256, 0, stream>>>(tgtp, deg);
  k_bounds<<<(NN + 255) / 256, 256, 0, stream>>>(batch, gstart, gend);
  k_lin0<<<(NN * DDIM + 255) / 256, 256, 0, stream>>>(x, lin0_w, lin0_b, out);
  k_pack<<<(1032 * 512 + 255) / 256, 256, 0, stream>>>(en_w2, en_b2, w2pp);

  for (int step = 0; step < NSTEP; ++step) {
    hipMemsetAsync(agg, 0, (size_t)NN * 64 * 4, stream);
    k_msg<<<(NE + EPB - 1) / EPB, EPB, 0, stream>>>(out, ea, en_w1, en_b1, w2pp,
                                                    srcp, tgtp, agg);
    k_gru<<<NN / 8, 256, 0, stream>>>(agg, deg, conv_b, gru_wih, gru_whh, gru_bih,
                                      gru_bhh, out);
  }

  for (int step = 0; step < NSTEP; ++step) {
    k_lstm_g<<<NB, 256, 0, stream>>>(qstar, hl, lstm_wih, lstm_whh, lstm_bih,
                                     lstm_bhh, gbuf);
    k_lstm_upd<<<(NB * 64 + 255) / 256, 256, 0, stream>>>(gbuf, cl, hl);
    k_attn<<<NB, 64, 0, stream>>>(out, hl, gstart, gend, qstar);
  }

  k_final<<<NB, 64, 0, stream>>>(qstar, lin1_w, lin1_b, lin2_w, lin2_b, (float*)d_out);
}

// Round 3
// 1081.405 us; speedup vs baseline: 2.1973x; 2.1973x over previous
//
#include <hip/hip_runtime.h>
#include <hip/hip_bf16.h>
#include <math.h>

#define NN 15000
#define NE 60000
#define NB 512
#define NIF 15
#define EIF 5
#define EHID 128
#define NSTEP 6
#define EPB 128   // edges per k_msg block (2 waves x 64)

typedef _Float16 half8 __attribute__((ext_vector_type(8)));
typedef float floatx4 __attribute__((ext_vector_type(4)));

__device__ __forceinline__ float sigmoidf_(float x) { return 1.f / (1.f + expf(-x)); }

__global__ void k_sentinel(float* out) { out[0] = 1000.0f; }

// ---- fused setup: lin0 (+relu), degree, per-graph bounds ----
__global__ void k_setup(const float* __restrict__ x, const float* __restrict__ l0w,
                        const float* __restrict__ l0b, const int* __restrict__ tgt,
                        const int* __restrict__ batch, float* __restrict__ outv,
                        float* __restrict__ deg, int* __restrict__ gstart,
                        int* __restrict__ gend) {
  int idx = blockIdx.x * 256 + threadIdx.x;
  if (idx < NN * 64) {
    int n = idx >> 6, d = idx & 63;
    float s = l0b[d];
#pragma unroll
    for (int i = 0; i < NIF; ++i) s += x[n * NIF + i] * l0w[d * NIF + i];
    outv[idx] = fmaxf(s, 0.f);
  }
  if (idx < NE) atomicAdd(&deg[tgt[idx]], 1.0f);
  if (idx < NN) {
    int bb = batch[idx];
    atomicMin(&gstart[bb], idx);
    atomicMax(&gend[bb], idx + 1);
  }
}

// ---- fused pack: w2pp (edge-net B-frags), gru wgpk (B-frags), lstm transposed ----
// w2pp: idx<528384, layout [g<1032][o<64][j<8]; g<1024: k=g*8+j, i=k>>7, h=k&127,
//       val=w2[(i*64+o)*128+h]; g>=1024: i=(g-1024)*8+j, val=b2[i*64+o].
// wgpk: 24576 f16: [(kind*2+cc)<4][o<192][r<32], val=W[o][cc*32+r] (kind0=ih,1=hh)
// wTih: 32768 f32: [k<128][g<256] = lstm_wih[g*128+k]
// wThh: 16384 f32: [k<64][g<256]  = lstm_whh[g*64+k]
__global__ void k_packall(const float* __restrict__ w2, const float* __restrict__ b2,
                          const float* __restrict__ gwih, const float* __restrict__ gwhh,
                          const float* __restrict__ lwih, const float* __restrict__ lwhh,
                          _Float16* __restrict__ w2pp, _Float16* __restrict__ wgpk,
                          float* __restrict__ wTih, float* __restrict__ wThh) {
  int idx = blockIdx.x * 256 + threadIdx.x;
  if (idx < 528384) {
    int g = idx >> 9;
    int r = idx & 511;
    int o = r >> 3, j = r & 7;
    float v;
    if (g < 1024) {
      int i = g >> 4;
      int h = ((g & 15) << 3) + j;
      v = w2[(size_t)(i * 64 + o) * 128 + h];
    } else {
      int i = ((g - 1024) << 3) + j;
      v = b2[i * 64 + o];
    }
    w2pp[idx] = (_Float16)v;
  } else if (idx < 528384 + 24576) {
    int i2 = idx - 528384;
    int kc = i2 / 6144;          // (kind*2+cc)
    int rem = i2 % 6144;
    int o = rem >> 5, r = rem & 31;
    int kind = kc >> 1, cc = kc & 1;
    float v = kind ? gwhh[o * 64 + cc * 32 + r] : gwih[o * 64 + cc * 32 + r];
    wgpk[i2] = (_Float16)v;
  } else if (idx < 528384 + 24576 + 32768) {
    int i3 = idx - (528384 + 24576);
    int k = i3 >> 8, g = i3 & 255;
    wTih[i3] = lwih[g * 128 + k];
  } else if (idx < 528384 + 24576 + 32768 + 16384) {
    int i4 = idx - (528384 + 24576 + 32768);
    int k = i4 >> 8, g = i4 & 255;
    wThh[i4] = lwhh[g * 64 + k];
  }
}

// ---- fused message pass, 4-way K-split ----
// blockIdx.x: edge group (128 edges); blockIdx.y = split: ib=y>>1 (i-range 32),
// hb=y&1 (h-range 64). K-chunks c=(ib*32+il)*4+hb*2+hc, il<32, hc<2 (64 chunks),
// plus bias chunk 256+ib on hb==0 blocks. hid A-frags are loop-invariant per split.
__global__ __launch_bounds__(128, 3) void k_msg(
    const float* __restrict__ outv, const float* __restrict__ ea,
    const float* __restrict__ w1, const float* __restrict__ b1,
    const _Float16* __restrict__ w2pp, const int* __restrict__ src,
    const int* __restrict__ tgt, float* __restrict__ agg) {
  __shared__ __align__(16) _Float16 hidL[EPB][72];  // h-range 64 + pad8
  __shared__ __align__(16) _Float16 osL[EPB][40];   // i-range 32 + pad8
  __shared__ float w1L[384];                        // 64x5 w1 + 64 b1 (h-range)
  int tid = threadIdx.x;
  int e0 = blockIdx.x * EPB;
  int ib = blockIdx.y >> 1, hb = blockIdx.y & 1;

  for (int idx = tid; idx < 384; idx += EPB)
    w1L[idx] = (idx < 320) ? w1[hb * 320 + idx] : b1[hb * 64 + idx - 320];

  int e = e0 + tid;
  bool valid = e < NE;
  int s = valid ? src[e] : 0;
  const float4* op = (const float4*)(outv + (size_t)s * 64 + ib * 32);
#pragma unroll
  for (int qq = 0; qq < 8; ++qq) {
    float4 v = op[qq];
    if (!valid) v = make_float4(0.f, 0.f, 0.f, 0.f);
    osL[tid][qq * 4 + 0] = (_Float16)v.x;
    osL[tid][qq * 4 + 1] = (_Float16)v.y;
    osL[tid][qq * 4 + 2] = (_Float16)v.z;
    osL[tid][qq * 4 + 3] = (_Float16)v.w;
  }
  float eav[EIF];
#pragma unroll
  for (int i = 0; i < EIF; ++i) eav[i] = valid ? ea[e * EIF + i] : 0.f;
  __syncthreads();  // w1L ready
  for (int hh = 0; hh < 64; ++hh) {
    float sum = w1L[320 + hh];
#pragma unroll
    for (int i = 0; i < EIF; ++i) sum += eav[i] * w1L[hh * EIF + i];
    hidL[tid][hh] = (_Float16)fmaxf(sum, 0.f);
  }
  __syncthreads();

  int wv = tid >> 6, lane = tid & 63;
  int l15 = lane & 15, q = lane >> 4;
  int rbase = wv * 64 + l15;

  // loop-invariant hid A-frags (h-range fixed per split)
  half8 hidf[4][2];
#pragma unroll
  for (int m = 0; m < 4; ++m)
#pragma unroll
    for (int hc = 0; hc < 2; ++hc)
      hidf[m][hc] = *(const half8*)&hidL[rbase + m * 16][hc * 32 + q * 8];

  floatx4 acc[4][4];
#pragma unroll
  for (int m = 0; m < 4; ++m)
#pragma unroll
    for (int og = 0; og < 4; ++og) acc[m][og] = (floatx4){0.f, 0.f, 0.f, 0.f};

  for (int il4 = 0; il4 < 32; il4 += 4) {
#pragma unroll
    for (int u = 0; u < 4; ++u) {
      int il = il4 + u;
      _Float16 osv[4];
#pragma unroll
      for (int m = 0; m < 4; ++m) osv[m] = osL[rbase + m * 16][il];
#pragma unroll
      for (int hc = 0; hc < 2; ++hc) {
        int c = (ib * 32 + il) * 4 + hb * 2 + hc;
        const _Float16* bp = w2pp + ((size_t)(c * 4 + q) * 64 + l15) * 8;
        half8 af[4];
#pragma unroll
        for (int m = 0; m < 4; ++m) {
          half8 osp = {osv[m], osv[m], osv[m], osv[m], osv[m], osv[m], osv[m], osv[m]};
          af[m] = hidf[m][hc] * osp;
        }
#pragma unroll
        for (int og = 0; og < 4; ++og) {
          half8 bf = *(const half8*)(bp + og * 128);
#pragma unroll
          for (int m = 0; m < 4; ++m)
            acc[m][og] = __builtin_amdgcn_mfma_f32_16x16x32_f16(af[m], bf, acc[m][og], 0, 0, 0);
        }
      }
    }
  }

  if (hb == 0) {  // bias chunk: A = os directly; i-range matches ib exactly
    int cb = 256 + ib;
    const _Float16* bp = w2pp + ((size_t)(cb * 4 + q) * 64 + l15) * 8;
    half8 af[4];
#pragma unroll
    for (int m = 0; m < 4; ++m)
      af[m] = *(const half8*)&osL[rbase + m * 16][q * 8];
#pragma unroll
    for (int og = 0; og < 4; ++og) {
      half8 bf = *(const half8*)(bp + og * 128);
#pragma unroll
      for (int m = 0; m < 4; ++m)
        acc[m][og] = __builtin_amdgcn_mfma_f32_16x16x32_f16(af[m], bf, acc[m][og], 0, 0, 0);
    }
  }

  // epilogue: C/D row=(lane>>4)*4+j (edge), col=lane&15
#pragma unroll
  for (int m = 0; m < 4; ++m) {
    int erow = e0 + wv * 64 + m * 16 + q * 4;
#pragma unroll
    for (int j = 0; j < 4; ++j) {
      int ee = erow + j;
      if (ee < NE) {
        int t = tgt[ee];
        float* ap = agg + (size_t)t * 64 + l15;
#pragma unroll
        for (int og = 0; og < 4; ++og) atomicAdd(ap + og * 16, acc[m][og][j]);
      }
    }
  }
}

// ---- GRU step via MFMA: gates = [m,h](f16) @ [Wih;Whh]^T; fused nonlinearity.
// 64 nodes/block, 4 waves; wave w owns gate cols {w*16..+16} of r,z,n tiles.
// Also zeroes agg in-place (after reading) for the next step's atomics.
__global__ __launch_bounds__(256, 2) void k_gru(
    float* __restrict__ agg, const float* __restrict__ deg,
    const float* __restrict__ convb, const _Float16* __restrict__ wgpk,
    const float* __restrict__ bih, const float* __restrict__ bhh,
    float* __restrict__ outv) {
  __shared__ __align__(16) _Float16 aL[64][136];  // K=128 + pad8
  __shared__ float hF[64][68];
  __shared__ float cbL[64];
  int tid = threadIdx.x;
  int n0 = blockIdx.x * 64;
  if (tid < 64) cbL[tid] = convb[tid];
  __syncthreads();

  int nl = tid >> 2, dq = (tid & 3) * 16;
  int n = n0 + nl;
  if (n < NN) {
    float dg = fmaxf(deg[n], 1.f);
    const float4* ap = (const float4*)(agg + (size_t)n * 64 + dq);
    const float4* hp = (const float4*)(outv + (size_t)n * 64 + dq);
    float4* az = (float4*)(agg + (size_t)n * 64 + dq);
#pragma unroll
    for (int t = 0; t < 4; ++t) {
      float4 a = ap[t];
      float4 h = hp[t];
      int d = dq + t * 4;
      aL[nl][d + 0] = (_Float16)fmaxf(a.x / dg + cbL[d + 0], 0.f);
      aL[nl][d + 1] = (_Float16)fmaxf(a.y / dg + cbL[d + 1], 0.f);
      aL[nl][d + 2] = (_Float16)fmaxf(a.z / dg + cbL[d + 2], 0.f);
      aL[nl][d + 3] = (_Float16)fmaxf(a.w / dg + cbL[d + 3], 0.f);
      aL[nl][64 + d + 0] = (_Float16)h.x;
      aL[nl][64 + d + 1] = (_Float16)h.y;
      aL[nl][64 + d + 2] = (_Float16)h.z;
      aL[nl][64 + d + 3] = (_Float16)h.w;
      hF[nl][d + 0] = h.x; hF[nl][d + 1] = h.y;
      hF[nl][d + 2] = h.z; hF[nl][d + 3] = h.w;
      az[t] = make_float4(0.f, 0.f, 0.f, 0.f);
    }
  } else {
#pragma unroll
    for (int t = 0; t < 4; ++t) {
      int d = dq + t * 4;
#pragma unroll
      for (int u = 0; u < 4; ++u) {
        aL[nl][d + u] = (_Float16)0.f;
        aL[nl][64 + d + u] = (_Float16)0.f;
        hF[nl][d + u] = 0.f;
      }
    }
  }
  __syncthreads();

  int wv = tid >> 6, lane = tid & 63, l15 = lane & 15, qd = lane >> 4;
  floatx4 acc[4][3][2];
#pragma unroll
  for (int mt = 0; mt < 4; ++mt)
#pragma unroll
    for (int tt = 0; tt < 3; ++tt)
#pragma unroll
      for (int kind = 0; kind < 2; ++kind) acc[mt][tt][kind] = (floatx4){0.f, 0.f, 0.f, 0.f};

#pragma unroll
  for (int kind = 0; kind < 2; ++kind) {
#pragma unroll
    for (int cc = 0; cc < 2; ++cc) {
      half8 af[4];
#pragma unroll
      for (int mt = 0; mt < 4; ++mt)
        af[mt] = *(const half8*)&aL[mt * 16 + l15][kind * 64 + cc * 32 + qd * 8];
#pragma unroll
      for (int tt = 0; tt < 3; ++tt) {
        int gb = (tt * 4 + wv) * 16;
        half8 bf = *(const half8*)&wgpk[((size_t)(kind * 2 + cc) * 192 + gb + l15) * 32 + qd * 8];
#pragma unroll
        for (int mt = 0; mt < 4; ++mt)
          acc[mt][tt][kind] = __builtin_amdgcn_mfma_f32_16x16x32_f16(af[mt], bf, acc[mt][tt][kind], 0, 0, 0);
      }
    }
  }

  int d = wv * 16 + l15;
  float bir = bih[d], bhr = bhh[d];
  float biz = bih[64 + d], bhz = bhh[64 + d];
  float bin = bih[128 + d], bhn = bhh[128 + d];
#pragma unroll
  for (int mt = 0; mt < 4; ++mt) {
#pragma unroll
    for (int j = 0; j < 4; ++j) {
      int nloc = mt * 16 + qd * 4 + j;
      int nn = n0 + nloc;
      if (nn < NN) {
        float ir = acc[mt][0][0][j] + bir, hr = acc[mt][0][1][j] + bhr;
        float iz = acc[mt][1][0][j] + biz, hz = acc[mt][1][1][j] + bhz;
        float in_ = acc[mt][2][0][j] + bin, hn = acc[mt][2][1][j] + bhn;
        float r = sigmoidf_(ir + hr);
        float z = sigmoidf_(iz + hz);
        float ng = tanhf(in_ + r * hn);
        float h = hF[nloc][d];
        outv[(size_t)nn * 64 + d] = (1.f - z) * ng + z * h;
      }
    }
  }
}

// ---- fully fused Set2Set (6 steps) + head, one block per graph ----
__global__ __launch_bounds__(256) void k_s2s(
    const float* __restrict__ outv, const int* __restrict__ gstart,
    const int* __restrict__ gend, const float* __restrict__ wTih,
    const float* __restrict__ wThh, const float* __restrict__ bih,
    const float* __restrict__ bhh, const float* __restrict__ l1w,
    const float* __restrict__ l1b, const float* __restrict__ l2w,
    const float* __restrict__ l2b, float* __restrict__ y) {
  __shared__ float qL[128], hlL[64], clL[64], gL[256];
  __shared__ float mxA[4], smA[4], accA[4][64], hidL[64];
  int b = blockIdx.x, tid = threadIdx.x, wv = tid >> 6, lane = tid & 63;
  int s0 = gstart[b], e0 = gend[b];
  if (s0 > e0) { s0 = 0; e0 = 0; }
  if (tid < 128) qL[tid] = 0.f;
  if (tid < 64) { hlL[tid] = 0.f; clL[tid] = 0.f; }
  __syncthreads();

  for (int step = 0; step < NSTEP; ++step) {
    {  // LSTM gates, one per thread (coalesced via transposed weights)
      int g = tid;
      float s = bih[g] + bhh[g];
      for (int k = 0; k < 128; ++k) s += qL[k] * wTih[k * 256 + g];
      for (int k = 0; k < 64; ++k) s += hlL[k] * wThh[k * 256 + g];
      gL[g] = s;
    }
    __syncthreads();
    if (tid < 64) {
      float ig = gL[tid], fg = gL[64 + tid], gg = gL[128 + tid], og = gL[192 + tid];
      float c = sigmoidf_(fg) * clL[tid] + sigmoidf_(ig) * tanhf(gg);
      clL[tid] = c;
      hlL[tid] = sigmoidf_(og) * tanhf(c);
    }
    __syncthreads();
    // attention: waves split nodes strided; two passes (max, then sum/acc)
    float hd = hlL[lane];
    float mxw = -1e30f;
    for (int nn = s0 + wv; nn < e0; nn += 4) {
      float v = outv[(size_t)nn * 64 + lane] * hd;
#pragma unroll
      for (int off = 32; off > 0; off >>= 1) v += __shfl_xor(v, off);
      mxw = fmaxf(mxw, v);
    }
    if (lane == 0) mxA[wv] = mxw;
    __syncthreads();
    float mx = fmaxf(fmaxf(mxA[0], mxA[1]), fmaxf(mxA[2], mxA[3]));
    float sm = 0.f, ac = 0.f;
    for (int nn = s0 + wv; nn < e0; nn += 4) {
      float o_nd = outv[(size_t)nn * 64 + lane];
      float v = o_nd * hd;
#pragma unroll
      for (int off = 32; off > 0; off >>= 1) v += __shfl_xor(v, off);
      float ex = expf(v - mx);
      sm += ex;
      ac += ex * o_nd;
    }
    if (lane == 0) smA[wv] = sm;
    accA[wv][lane] = ac;
    __syncthreads();
    if (tid < 64) {
      float den = smA[0] + smA[1] + smA[2] + smA[3] + 1e-16f;
      float rv = (accA[0][tid] + accA[1][tid] + accA[2][tid] + accA[3][tid]) / den;
      qL[tid] = hlL[tid];
      qL[64 + tid] = rv;
    }
    __syncthreads();
  }
  // head
  if (tid < 64) {
    float s = l1b[tid];
    for (int k = 0; k < 128; ++k) s += qL[k] * l1w[tid * 128 + k];
    hidL[tid] = fmaxf(s, 0.f);
  }
  __syncthreads();
  if (tid < 12) {
    float s = l2b[tid];
    for (int k = 0; k < 64; ++k) s += hidL[k] * l2w[tid * 64 + k];
    y[b * 12 + tid] = s;
  }
}

extern "C" void kernel_launch(void* const* d_in, const int* in_sizes, int n_in,
                              void* d_out, int out_size, void* d_ws, size_t ws_size,
                              hipStream_t stream) {
  const float* x = (const float*)d_in[0];
  const float* ea = (const float*)d_in[1];
  const int* eidx = (const int*)d_in[2];
  const int* batch = (const int*)d_in[3];
  const float* lin0_w = (const float*)d_in[4];
  const float* lin0_b = (const float*)d_in[5];
  const float* en_w1 = (const float*)d_in[6];
  const float* en_b1 = (const float*)d_in[7];
  const float* en_w2 = (const float*)d_in[8];
  const float* en_b2 = (const float*)d_in[9];
  const float* conv_b = (const float*)d_in[10];
  const float* gru_wih = (const float*)d_in[11];
  const float* gru_whh = (const float*)d_in[12];
  const float* gru_bih = (const float*)d_in[13];
  const float* gru_bhh = (const float*)d_in[14];
  const float* lstm_wih = (const float*)d_in[15];
  const float* lstm_whh = (const float*)d_in[16];
  const float* lstm_bih = (const float*)d_in[17];
  const float* lstm_bhh = (const float*)d_in[18];
  const float* lin1_w = (const float*)d_in[19];
  const float* lin1_b = (const float*)d_in[20];
  const float* lin2_w = (const float*)d_in[21];
  const float* lin2_b = (const float*)d_in[22];
  const int* srcp = eidx;
  const int* tgtp = eidx + NE;

  char* ws = (char*)d_ws;
  size_t off = 0;
  auto alloc = [&](size_t bytes) {
    char* p = ws + off;
    off += (bytes + 255) & ~(size_t)255;
    return p;
  };
  _Float16* w2pp = (_Float16*)alloc((size_t)1032 * 512 * 2);  // 1.06 MB
  _Float16* wgpk = (_Float16*)alloc((size_t)24576 * 2);
  float* wTih = (float*)alloc((size_t)32768 * 4);
  float* wThh = (float*)alloc((size_t)16384 * 4);
  float* out = (float*)alloc((size_t)NN * 64 * 4);
  float* agg = (float*)alloc((size_t)NN * 64 * 4);
  float* deg = (float*)alloc((size_t)NN * 4);
  int* gstart = (int*)alloc((size_t)NB * 4);
  int* gend = (int*)alloc((size_t)NB * 4);
  if (off > ws_size) {
    k_sentinel<<<1, 1, 0, stream>>>((float*)d_out);
    return;
  }

  hipMemsetAsync(deg, 0, (size_t)NN * 4, stream);
  hipMemsetAsync(gstart, 0x7f, (size_t)NB * 4, stream);
  hipMemsetAsync(gend, 0, (size_t)NB * 4, stream);
  hipMemsetAsync(agg, 0, (size_t)NN * 64 * 4, stream);

  k_setup<<<(NN * 64 + 255) / 256, 256, 0, stream>>>(x, lin0_w, lin0_b, tgtp, batch,
                                                     out, deg, gstart, gend);
  k_packall<<<(528384 + 24576 + 32768 + 16384 + 255) / 256, 256, 0, stream>>>(
      en_w2, en_b2, gru_wih, gru_whh, lstm_wih, lstm_whh, w2pp, wgpk, wTih, wThh);

  for (int step = 0; step < NSTEP; ++step) {
    k_msg<<<dim3((NE + EPB - 1) / EPB, 4), EPB, 0, stream>>>(out, ea, en_w1, en_b1,
                                                             w2pp, srcp, tgtp, agg);
    k_gru<<<(NN + 63) / 64, 256, 0, stream>>>(agg, deg, conv_b, wgpk, gru_bih,
                                              gru_bhh, out);
  }

  k_s2s<<<NB, 256, 0, stream>>>(out, gstart, gend, wTih, wThh, lstm_bih, lstm_bhh,
                                lin1_w, lin1_b, lin2_w, lin2_b, (float*)d_out);
}